// Round 12
// baseline (83.932 us; speedup 1.0000x reference)
//
#include <hip/hip_runtime.h>
#include <hip/hip_bf16.h>

// Problem constants
#define N_IN   65536
#define N_OUTP 16384
#define KNB    16
#define FDIM   64
#define M_DIM  32          // N_DIST * N_PHI
#define KDIM   2048        // M_DIM * FDIM
#define OUT_D  256

typedef __bf16 bf16x8_t __attribute__((ext_vector_type(8)));
typedef float  f32x4_t  __attribute__((ext_vector_type(4)));
typedef float  f32x2_t  __attribute__((ext_vector_type(2)));

// ---------------------------------------------------------------------------
// A storage ("stream" layout): per 16-row tile T (=row>>4), per K32-chunk kk,
// 64 lanes x 16B. Lane l holds row (l&15), kg in [kk*32+(l>>4)*8, +8).
// u128 index = T*4096 + kk*64 + l.
// ---------------------------------------------------------------------------

__device__ __forceinline__ unsigned pk2(float a, float b) {
  __bf16 b0 = (__bf16)a, b1 = (__bf16)b;
  return ((unsigned)__builtin_bit_cast(unsigned short, b1) << 16) |
          (unsigned)__builtin_bit_cast(unsigned short, b0);
}
__device__ __forceinline__ float ulo(unsigned u) {
  return __builtin_bit_cast(float, u << 16);
}
__device__ __forceinline__ float uhi(unsigned u) {
  return __builtin_bit_cast(float, u & 0xffff0000u);
}

// ---------------------------------------------------------------------------
// pack_B v2: one block per K32-slab (64 blocks). Coalesced float4 load of
// W rows [kk*32,+32) into padded LDS, then emit bf16 B-fragments coalesced.
// ---------------------------------------------------------------------------
__global__ __launch_bounds__(256) void pack_B_kernel(
    const float* __restrict__ W, uint4* __restrict__ Bws)
{
  __shared__ float wlds[32 * 260];
  const int kk = blockIdx.x;
  const int t  = threadIdx.x;

  const float4* Wb = (const float4*)(W + kk * 32 * OUT_D);
#pragma unroll
  for (int i = 0; i < 8; ++i) {
    int idx = i * 256 + t;
    int row = idx >> 6, c4 = idx & 63;
    float4 v = Wb[idx];
    *(float4*)(wlds + row * 260 + c4 * 4) = v;
  }
  __syncthreads();

#pragma unroll
  for (int j = 0; j < 4; ++j) {
    int c  = j * 256 + t;
    int l  = c & 63, nt = c >> 6;
    int r0 = (l >> 4) * 8, col = nt * 16 + (l & 15);
    union { unsigned short s[8]; uint4 v; } u;
#pragma unroll
    for (int jj = 0; jj < 8; ++jj) {
      __bf16 b = (__bf16)wlds[(r0 + jj) * 260 + col];
      u.s[jj] = __builtin_bit_cast(unsigned short, b);
    }
    Bws[(size_t)kk * 1024 + c] = u.v;
  }
}

// ---------------------------------------------------------------------------
// agg v5: weights -> LDS as PACKED BF16 (1 b128 w-read per k in einsum);
// gather x -> LDS as packed bf16 (1 b128 x-read per k). LDS 28.1 KB ->
// 5 blocks/CU. XCD co-location swizzle: agg work w runs on the same XCD
// where gemm block (w>>3) will read its output tiles.
//   wb  strides (u32): r8*324, k*20  (16 data + 4 pad)
//   xpk strides (u32): r8*576, k*36  (32 data + 4 pad)
// ---------------------------------------------------------------------------
#define WBST 324
#define WBK  20
#define XPS  576
#define XPK  36

__global__ __launch_bounds__(256, 5) void agg_kernel(
    const float* __restrict__ x,
    const float* __restrict__ d_dists,
    const float* __restrict__ d_phi,
    const float* __restrict__ dists,
    const float* __restrict__ sigma_p,
    const float* __restrict__ kappa_p,
    const float* __restrict__ phi,
    const int*   __restrict__ nh_idx,
    uint4*       __restrict__ Aws)     // stream layout
{
  __shared__ __align__(16) unsigned wb[8 * WBST];    // 10368 B
  __shared__ __align__(16) unsigned xpk[8 * XPS];    // 18432 B

  const int t = threadIdx.x;
  // bijective bit-swap (2048 = 2^11 blocks): work w lands on XCD (w>>3)&7
  const int b = blockIdx.x;
  const int w = (b & ~63) | ((b & 7) << 3) | ((b >> 3) & 7);
  const int n0 = w * 8;
  const int T  = w >> 1;          // 16-row tile index
  const int r0 = (w & 1) * 8;     // row offset within tile

  // ---- Phase 0a: issue x gather early. (h=t&1, gk=(t>>1)&15, gr8=t>>5)
  const int h = t & 1, gk = (t >> 1) & 15, gr8 = t >> 5;
  const int gidx = nh_idx[(n0 + gr8) * KNB + gk];
  const float4* xr = (const float4*)x + (size_t)gidx * 16 + h * 8;
  float4 xreg[8];
#pragma unroll
  for (int j = 0; j < 8; ++j) xreg[j] = xr[j];

  // ---- Phase 0b: weights (packed bf16) while gather is in flight.
  {
    const float sinv = 1.0f / sigma_p[0];
    const float kap  = kappa_p[0];
    float phiv[8], distv[4];
#pragma unroll
    for (int p = 0; p < 8; ++p) phiv[p] = phi[p];
#pragma unroll
    for (int d = 0; d < 4; ++d) distv[d] = dists[d];

    int rk = t >> 1, r8w = rk >> 4, k = rk & 15, rep = t & 1;
    int n = n0 + r8w;
    float dd = d_dists[n * KNB + k];
    float dp = d_phi[n * KNB + k];
    float wp[8];
#pragma unroll
    for (int p = 0; p < 8; ++p) wp[p] = __expf(kap * __cosf(dp - phiv[p]));

    unsigned* dst = wb + r8w * WBST + k * WBK + rep * 8;
#pragma unroll
    for (int dl = 0; dl < 2; ++dl) {
      int d = rep * 2 + dl;
      float td = (dd - distv[d]) * sinv;
      float wd = __expf(-0.5f * td * td);
      uint4 v;
      v.x = pk2(wd * wp[0], wd * wp[1]);
      v.y = pk2(wd * wp[2], wd * wp[3]);
      v.z = pk2(wd * wp[4], wd * wp[5]);
      v.w = pk2(wd * wp[6], wd * wp[7]);
      *(uint4*)(dst + dl * 4) = v;
    }
  }

  // ---- Phase 0c: commit gather to xpk as packed bf16 (row half h).
  {
    unsigned u[16];
#pragma unroll
    for (int j = 0; j < 8; ++j) {
      u[2 * j]     = pk2(xreg[j].x, xreg[j].y);
      u[2 * j + 1] = pk2(xreg[j].z, xreg[j].w);
    }
    uint4* xd = (uint4*)(xpk + gr8 * XPS + gk * XPK + h * 16);
#pragma unroll
    for (int q = 0; q < 4; ++q)
      xd[q] = make_uint4(u[4 * q], u[4 * q + 1], u[4 * q + 2], u[4 * q + 3]);
  }
  __syncthreads();

  // ---- Phase 1: normalize wb in place. 128 active: (nr8 = t>>4, mc = t&15)
  if (t < 128) {
    int nr8 = t >> 4, mc = t & 15;
    unsigned* col = wb + nr8 * WBST + mc;
    unsigned v[16];
    float s0 = 0.f, s1 = 0.f;
#pragma unroll
    for (int k = 0; k < 16; ++k) {
      v[k] = col[k * WBK];
      s0 += ulo(v[k]);
      s1 += uhi(v[k]);
    }
    float i0 = 1.0f / (s0 + 1e-9f);
    float i1 = 1.0f / (s1 + 1e-9f);
#pragma unroll
    for (int k = 0; k < 16; ++k)
      col[k * WBK] = pk2(ulo(v[k]) * i0, uhi(v[k]) * i1);
  }
  __syncthreads();

  // ---- Phase 2: einsum 8m x 8f per thread (packed f32x2 FMA);
  // thread -> (r8 = t&7, fo = (t>>3)&7 [f-octet], mq = t>>6 [m-quad of 8])
  {
    const int r8 = t & 7, fo = (t >> 3) & 7, mq = t >> 6;
    f32x2_t acc[8][4];
#pragma unroll
    for (int mi = 0; mi < 8; ++mi)
#pragma unroll
      for (int fj = 0; fj < 4; ++fj) acc[mi][fj] = (f32x2_t){0.f, 0.f};

    const unsigned* xp_ = xpk + r8 * XPS + fo * 4;
    const unsigned* wp_ = wb + r8 * WBST + mq * 4;

#pragma unroll 8
    for (int k = 0; k < 16; ++k) {
      uint4 xu = *(const uint4*)(xp_ + k * XPK);
      uint4 wu = *(const uint4*)(wp_ + k * WBK);
      float wm[8] = {ulo(wu.x), uhi(wu.x), ulo(wu.y), uhi(wu.y),
                     ulo(wu.z), uhi(wu.z), ulo(wu.w), uhi(wu.w)};
      f32x2_t xv[4];
      xv[0] = (f32x2_t){ulo(xu.x), uhi(xu.x)};
      xv[1] = (f32x2_t){ulo(xu.y), uhi(xu.y)};
      xv[2] = (f32x2_t){ulo(xu.z), uhi(xu.z)};
      xv[3] = (f32x2_t){ulo(xu.w), uhi(xu.w)};
#pragma unroll
      for (int mi = 0; mi < 8; ++mi) {
        f32x2_t wmm = (f32x2_t){wm[mi], wm[mi]};
#pragma unroll
        for (int fj = 0; fj < 4; ++fj)
          acc[mi][fj] += wmm * xv[fj];
      }
    }

    // chunk for (row r0+r8, m = mq*8+mi, f in [fo*8, fo*8+8)):
    // u128 idx = T*4096 + (m*2 + (fo>>2))*64 + (fo&3)*16 + (r0+r8)
    uint4* base = Aws + (size_t)T * 4096 + (fo & 3) * 16 + r0 + r8
                      + (size_t)(fo >> 2) * 64;
#pragma unroll
    for (int mi = 0; mi < 8; ++mi) {
      int m = mq * 8 + mi;
      uint4 v;
      v.x = pk2(acc[mi][0][0], acc[mi][0][1]);
      v.y = pk2(acc[mi][1][0], acc[mi][1][1]);
      v.z = pk2(acc[mi][2][0], acc[mi][2][1]);
      v.w = pk2(acc[mi][3][0], acc[mi][3][1]);
      base[m * 128] = v;
    }
  }
}

// ---------------------------------------------------------------------------
// gemm v4 (K-split wave pairs): out(16384x256) = A(stream) @ B(frags).
// 256 blocks x 512 threads. Block = 64 rows x 256 cols. Wave w:
//   cg = w&3 (64-col group), half = w>>2 (kk parity). Each wave: 32 j-iters,
//   kk = 2j+half, cacc[4][4], 16 MFMA per iter, depth-4 register prefetch.
// Epilogue: half=0 parks partials in padded LDS; barrier; half=1 adds+stores.
// ---------------------------------------------------------------------------
__global__ __launch_bounds__(512, 2) void gemm_kernel(
    const uint4* __restrict__ Astream,
    const uint4* __restrict__ Bws,
    float*       __restrict__ out)
{
  __shared__ float red[4][64 * 68];   // 69632 B

  const int t    = threadIdx.x;
  const int lane = t & 63;
  const int w    = t >> 6;
  const int cg   = w & 3;        // col group (64 cols)
  const int half = w >> 2;       // kk parity
  const int rb   = blockIdx.x;   // 64-row block

  const uint4* pa = Astream + (size_t)(rb * 4) * 4096 + half * 64 + lane;
  const uint4* pb = Bws + (half * 16 + cg * 4) * 64 + lane;

  f32x4_t cacc[4][4];
#pragma unroll
  for (int mt = 0; mt < 4; ++mt)
#pragma unroll
    for (int i = 0; i < 4; ++i)
      cacc[mt][i] = (f32x4_t){0.f, 0.f, 0.f, 0.f};

  uint4 a[4][4], b[4][4];
#pragma unroll
  for (int s = 0; s < 4; ++s) {
#pragma unroll
    for (int mt = 0; mt < 4; ++mt) a[s][mt] = pa[mt * 4096 + s * 128];
#pragma unroll
    for (int i = 0; i < 4; ++i)    b[s][i]  = pb[s * 2048 + i * 64];
  }

#pragma unroll 4
  for (int j = 0; j < 32; ++j) {
    const int s = j & 3;
    bf16x8_t B0 = __builtin_bit_cast(bf16x8_t, b[s][0]);
    bf16x8_t B1 = __builtin_bit_cast(bf16x8_t, b[s][1]);
    bf16x8_t B2 = __builtin_bit_cast(bf16x8_t, b[s][2]);
    bf16x8_t B3 = __builtin_bit_cast(bf16x8_t, b[s][3]);
#pragma unroll
    for (int mt = 0; mt < 4; ++mt) {
      bf16x8_t A = __builtin_bit_cast(bf16x8_t, a[s][mt]);
      cacc[mt][0] = __builtin_amdgcn_mfma_f32_16x16x32_bf16(A, B0, cacc[mt][0], 0, 0, 0);
      cacc[mt][1] = __builtin_amdgcn_mfma_f32_16x16x32_bf16(A, B1, cacc[mt][1], 0, 0, 0);
      cacc[mt][2] = __builtin_amdgcn_mfma_f32_16x16x32_bf16(A, B2, cacc[mt][2], 0, 0, 0);
      cacc[mt][3] = __builtin_amdgcn_mfma_f32_16x16x32_bf16(A, B3, cacc[mt][3], 0, 0, 0);
    }
    if (j < 28) {
#pragma unroll
      for (int mt = 0; mt < 4; ++mt) a[s][mt] = pa[mt * 4096 + (j + 4) * 128];
#pragma unroll
      for (int i = 0; i < 4; ++i)    b[s][i]  = pb[(j + 4) * 2048 + i * 64];
    }
  }

  // C/D layout per 16x16 tile: col = lane&15, row = (lane>>4)*4 + reg
  const int lrow = (lane >> 4) * 4;
  const int lcol = lane & 15;

  if (half == 0) {
#pragma unroll
    for (int mt = 0; mt < 4; ++mt)
#pragma unroll
      for (int i = 0; i < 4; ++i)
#pragma unroll
        for (int reg = 0; reg < 4; ++reg)
          red[cg][(mt * 16 + lrow + reg) * 68 + i * 16 + lcol] = cacc[mt][i][reg];
  }
  __syncthreads();
  if (half == 1) {
#pragma unroll
    for (int mt = 0; mt < 4; ++mt)
#pragma unroll
      for (int i = 0; i < 4; ++i)
#pragma unroll
        for (int reg = 0; reg < 4; ++reg) {
          int row = mt * 16 + lrow + reg;
          int col = i * 16 + lcol;
          float v = red[cg][row * 68 + col] + cacc[mt][i][reg];
          out[(rb * 64 + row) * OUT_D + cg * 64 + col] = v;
        }
  }
}

// ===========================================================================
extern "C" void kernel_launch(void* const* d_in, const int* in_sizes, int n_in,
                              void* d_out, int out_size, void* d_ws, size_t ws_size,
                              hipStream_t stream) {
  const float* x      = (const float*)d_in[0];
  const float* dd     = (const float*)d_in[1];
  const float* dp     = (const float*)d_in[2];
  const float* dists  = (const float*)d_in[3];
  const float* sigma  = (const float*)d_in[4];
  const float* kappa  = (const float*)d_in[5];
  const float* phi    = (const float*)d_in[6];
  const float* W      = (const float*)d_in[7];
  const int*   nh     = (const int*)d_in[8];
  float*       out    = (float*)d_out;

  uint4* Bws = (uint4*)d_ws;                       // 1 MB of B-fragments
  uint4* Aws = (uint4*)((char*)d_ws + (1 << 20));  // 64 MB A, stream layout

  pack_B_kernel<<<64, 256, 0, stream>>>(W, Bws);
  agg_kernel<<<N_OUTP / 8, 256, 0, stream>>>(
      x, dd, dp, dists, sigma, kappa, phi, nh, Aws);
  gemm_kernel<<<N_OUTP / 64, 512, 0, stream>>>(Aws, Bws, out);
}

// Round 13
// 59.343 us; speedup vs baseline: 1.4144x; 1.4144x over previous
//
#include <hip/hip_runtime.h>
#include <hip/hip_bf16.h>

// Problem constants
#define N_IN   65536
#define N_OUTP 16384
#define KNB    16
#define FDIM   64
#define M_DIM  32          // N_DIST * N_PHI
#define KDIM   2048        // M_DIM * FDIM
#define OUT_D  256

typedef __bf16 bf16x8_t __attribute__((ext_vector_type(8)));
typedef float  f32x4_t  __attribute__((ext_vector_type(4)));
typedef float  f32x2_t  __attribute__((ext_vector_type(2)));

// ---------------------------------------------------------------------------
// A storage ("stream" layout): per 16-row tile T (=row>>4), per K32-chunk kk,
// 64 lanes x 16B. Lane l holds row (l&15), kg in [kk*32+(l>>4)*8, +8).
// u128 index = T*4096 + kk*64 + l.
// ---------------------------------------------------------------------------

__device__ __forceinline__ unsigned pk2(float a, float b) {
  __bf16 b0 = (__bf16)a, b1 = (__bf16)b;
  return ((unsigned)__builtin_bit_cast(unsigned short, b1) << 16) |
          (unsigned)__builtin_bit_cast(unsigned short, b0);
}
__device__ __forceinline__ float ulo(unsigned u) {
  return __builtin_bit_cast(float, u << 16);
}
__device__ __forceinline__ float uhi(unsigned u) {
  return __builtin_bit_cast(float, u & 0xffff0000u);
}

// ---------------------------------------------------------------------------
// pack_B v2 (identical to R10): one block per K32-slab (64 blocks).
// ---------------------------------------------------------------------------
__global__ __launch_bounds__(256) void pack_B_kernel(
    const float* __restrict__ W, uint4* __restrict__ Bws)
{
  __shared__ float wlds[32 * 260];
  const int kk = blockIdx.x;
  const int t  = threadIdx.x;

  const float4* Wb = (const float4*)(W + kk * 32 * OUT_D);
#pragma unroll
  for (int i = 0; i < 8; ++i) {
    int idx = i * 256 + t;
    int row = idx >> 6, c4 = idx & 63;
    float4 v = Wb[idx];
    *(float4*)(wlds + row * 260 + c4 * 4) = v;
  }
  __syncthreads();

#pragma unroll
  for (int j = 0; j < 4; ++j) {
    int c  = j * 256 + t;
    int l  = c & 63, nt = c >> 6;
    int r0 = (l >> 4) * 8, col = nt * 16 + (l & 15);
    union { unsigned short s[8]; uint4 v; } u;
#pragma unroll
    for (int jj = 0; jj < 8; ++jj) {
      __bf16 b = (__bf16)wlds[(r0 + jj) * 260 + col];
      u.s[jj] = __builtin_bit_cast(unsigned short, b);
    }
    Bws[(size_t)kk * 1024 + c] = u.v;
  }
}

// ---------------------------------------------------------------------------
// agg v6 = R10's agg + wb packed as bf16 (ONLY delta vs R10):
//   - einsum per k: 1 w-read (b128, 8-lane broadcast) + 1 x-read (b128)
//   - LDS 28.9 KB -> 5 blocks/CU by resources
//   - NO blockIdx swizzle (R12's write-amplification culprit), lb(256,4)
//   wb  strides (u32): r8*324, k*20  (16 data + 4 pad; 324 mod 32 = 4)
//   xpk strides (u32): r8*576, k*36  (identical to R10)
// ---------------------------------------------------------------------------
#define WBST 324
#define WBK  20
#define XPS  576
#define XPK  36

__global__ __launch_bounds__(256, 4) void agg_kernel(
    const float* __restrict__ x,
    const float* __restrict__ d_dists,
    const float* __restrict__ d_phi,
    const float* __restrict__ dists,
    const float* __restrict__ sigma_p,
    const float* __restrict__ kappa_p,
    const float* __restrict__ phi,
    const int*   __restrict__ nh_idx,
    uint4*       __restrict__ Aws)     // stream layout
{
  __shared__ __align__(16) unsigned wb[8 * WBST];    // 10368 B
  __shared__ __align__(16) unsigned xpk[8 * XPS];    // 18432 B

  const int t  = threadIdx.x;
  const int n0 = blockIdx.x * 8;
  const int T  = blockIdx.x >> 1;          // 16-row tile index
  const int r0 = (blockIdx.x & 1) * 8;     // row offset within tile

  // ---- Phase 0a: issue x gather early. (h=t&1, gk=(t>>1)&15, gr8=t>>5)
  const int h = t & 1, gk = (t >> 1) & 15, gr8 = t >> 5;
  const int gidx = nh_idx[(n0 + gr8) * KNB + gk];
  const float4* xr = (const float4*)x + (size_t)gidx * 16 + h * 8;
  float4 xreg[8];
#pragma unroll
  for (int j = 0; j < 8; ++j) xreg[j] = xr[j];

  // ---- Phase 0b: weights (packed bf16) while gather is in flight.
  {
    const float sinv = 1.0f / sigma_p[0];
    const float kap  = kappa_p[0];
    float phiv[8], distv[4];
#pragma unroll
    for (int p = 0; p < 8; ++p) phiv[p] = phi[p];
#pragma unroll
    for (int d = 0; d < 4; ++d) distv[d] = dists[d];

    int rk = t >> 1, r8w = rk >> 4, k = rk & 15, rep = t & 1;
    int n = n0 + r8w;
    float dd = d_dists[n * KNB + k];
    float dp = d_phi[n * KNB + k];
    float wp[8];
#pragma unroll
    for (int p = 0; p < 8; ++p) wp[p] = __expf(kap * __cosf(dp - phiv[p]));

    unsigned* dst = wb + r8w * WBST + k * WBK + rep * 8;
#pragma unroll
    for (int dl = 0; dl < 2; ++dl) {
      int d = rep * 2 + dl;
      float td = (dd - distv[d]) * sinv;
      float wd = __expf(-0.5f * td * td);
      uint4 v;
      v.x = pk2(wd * wp[0], wd * wp[1]);
      v.y = pk2(wd * wp[2], wd * wp[3]);
      v.z = pk2(wd * wp[4], wd * wp[5]);
      v.w = pk2(wd * wp[6], wd * wp[7]);
      *(uint4*)(dst + dl * 4) = v;
    }
  }

  // ---- Phase 0c: commit gather to xpk as packed bf16 (row half h).
  {
    unsigned u[16];
#pragma unroll
    for (int j = 0; j < 8; ++j) {
      u[2 * j]     = pk2(xreg[j].x, xreg[j].y);
      u[2 * j + 1] = pk2(xreg[j].z, xreg[j].w);
    }
    uint4* xd = (uint4*)(xpk + gr8 * XPS + gk * XPK + h * 16);
#pragma unroll
    for (int q = 0; q < 4; ++q)
      xd[q] = make_uint4(u[4 * q], u[4 * q + 1], u[4 * q + 2], u[4 * q + 3]);
  }
  __syncthreads();

  // ---- Phase 1: normalize wb in place. 128 active: (nr8 = t>>4, mc = t&15)
  if (t < 128) {
    int nr8 = t >> 4, mc = t & 15;
    unsigned* col = wb + nr8 * WBST + mc;
    unsigned v[16];
    float s0 = 0.f, s1 = 0.f;
#pragma unroll
    for (int k = 0; k < 16; ++k) {
      v[k] = col[k * WBK];
      s0 += ulo(v[k]);
      s1 += uhi(v[k]);
    }
    float i0 = 1.0f / (s0 + 1e-9f);
    float i1 = 1.0f / (s1 + 1e-9f);
#pragma unroll
    for (int k = 0; k < 16; ++k)
      col[k * WBK] = pk2(ulo(v[k]) * i0, uhi(v[k]) * i1);
  }
  __syncthreads();

  // ---- Phase 2: einsum 8m x 8f per thread (packed f32x2 FMA);
  // thread -> (r8 = t&7, fo = (t>>3)&7 [f-octet], mq = t>>6 [m-quad of 8])
  {
    const int r8 = t & 7, fo = (t >> 3) & 7, mq = t >> 6;
    f32x2_t acc[8][4];
#pragma unroll
    for (int mi = 0; mi < 8; ++mi)
#pragma unroll
      for (int fj = 0; fj < 4; ++fj) acc[mi][fj] = (f32x2_t){0.f, 0.f};

    const unsigned* xp_ = xpk + r8 * XPS + fo * 4;
    const unsigned* wp_ = wb + r8 * WBST + mq * 4;

#pragma unroll 8
    for (int k = 0; k < 16; ++k) {
      uint4 xu = *(const uint4*)(xp_ + k * XPK);
      uint4 wu = *(const uint4*)(wp_ + k * WBK);
      float wm[8] = {ulo(wu.x), uhi(wu.x), ulo(wu.y), uhi(wu.y),
                     ulo(wu.z), uhi(wu.z), ulo(wu.w), uhi(wu.w)};
      f32x2_t xv[4];
      xv[0] = (f32x2_t){ulo(xu.x), uhi(xu.x)};
      xv[1] = (f32x2_t){ulo(xu.y), uhi(xu.y)};
      xv[2] = (f32x2_t){ulo(xu.z), uhi(xu.z)};
      xv[3] = (f32x2_t){ulo(xu.w), uhi(xu.w)};
#pragma unroll
      for (int mi = 0; mi < 8; ++mi) {
        f32x2_t wmm = (f32x2_t){wm[mi], wm[mi]};
#pragma unroll
        for (int fj = 0; fj < 4; ++fj)
          acc[mi][fj] += wmm * xv[fj];
      }
    }

    // chunk for (row r0+r8, m = mq*8+mi, f in [fo*8, fo*8+8)):
    // u128 idx = T*4096 + (m*2 + (fo>>2))*64 + (fo&3)*16 + (r0+r8)
    uint4* base = Aws + (size_t)T * 4096 + (fo & 3) * 16 + r0 + r8
                      + (size_t)(fo >> 2) * 64;
#pragma unroll
    for (int mi = 0; mi < 8; ++mi) {
      int m = mq * 8 + mi;
      uint4 v;
      v.x = pk2(acc[mi][0][0], acc[mi][0][1]);
      v.y = pk2(acc[mi][1][0], acc[mi][1][1]);
      v.z = pk2(acc[mi][2][0], acc[mi][2][1]);
      v.w = pk2(acc[mi][3][0], acc[mi][3][1]);
      base[m * 128] = v;
    }
  }
}

// ---------------------------------------------------------------------------
// gemm v4 (identical to R10): 256 blocks x 512 threads, K-split wave pairs.
// ---------------------------------------------------------------------------
__global__ __launch_bounds__(512, 2) void gemm_kernel(
    const uint4* __restrict__ Astream,
    const uint4* __restrict__ Bws,
    float*       __restrict__ out)
{
  __shared__ float red[4][64 * 68];   // 69632 B

  const int t    = threadIdx.x;
  const int lane = t & 63;
  const int w    = t >> 6;
  const int cg   = w & 3;        // col group (64 cols)
  const int half = w >> 2;       // kk parity
  const int rb   = blockIdx.x;   // 64-row block

  const uint4* pa = Astream + (size_t)(rb * 4) * 4096 + half * 64 + lane;
  const uint4* pb = Bws + (half * 16 + cg * 4) * 64 + lane;

  f32x4_t cacc[4][4];
#pragma unroll
  for (int mt = 0; mt < 4; ++mt)
#pragma unroll
    for (int i = 0; i < 4; ++i)
      cacc[mt][i] = (f32x4_t){0.f, 0.f, 0.f, 0.f};

  uint4 a[4][4], b[4][4];
#pragma unroll
  for (int s = 0; s < 4; ++s) {
#pragma unroll
    for (int mt = 0; mt < 4; ++mt) a[s][mt] = pa[mt * 4096 + s * 128];
#pragma unroll
    for (int i = 0; i < 4; ++i)    b[s][i]  = pb[s * 2048 + i * 64];
  }

#pragma unroll 4
  for (int j = 0; j < 32; ++j) {
    const int s = j & 3;
    bf16x8_t B0 = __builtin_bit_cast(bf16x8_t, b[s][0]);
    bf16x8_t B1 = __builtin_bit_cast(bf16x8_t, b[s][1]);
    bf16x8_t B2 = __builtin_bit_cast(bf16x8_t, b[s][2]);
    bf16x8_t B3 = __builtin_bit_cast(bf16x8_t, b[s][3]);
#pragma unroll
    for (int mt = 0; mt < 4; ++mt) {
      bf16x8_t A = __builtin_bit_cast(bf16x8_t, a[s][mt]);
      cacc[mt][0] = __builtin_amdgcn_mfma_f32_16x16x32_bf16(A, B0, cacc[mt][0], 0, 0, 0);
      cacc[mt][1] = __builtin_amdgcn_mfma_f32_16x16x32_bf16(A, B1, cacc[mt][1], 0, 0, 0);
      cacc[mt][2] = __builtin_amdgcn_mfma_f32_16x16x32_bf16(A, B2, cacc[mt][2], 0, 0, 0);
      cacc[mt][3] = __builtin_amdgcn_mfma_f32_16x16x32_bf16(A, B3, cacc[mt][3], 0, 0, 0);
    }
    if (j < 28) {
#pragma unroll
      for (int mt = 0; mt < 4; ++mt) a[s][mt] = pa[mt * 4096 + (j + 4) * 128];
#pragma unroll
      for (int i = 0; i < 4; ++i)    b[s][i]  = pb[(j + 4) * 2048 + i * 64];
    }
  }

  // C/D layout per 16x16 tile: col = lane&15, row = (lane>>4)*4 + reg
  const int lrow = (lane >> 4) * 4;
  const int lcol = lane & 15;

  if (half == 0) {
#pragma unroll
    for (int mt = 0; mt < 4; ++mt)
#pragma unroll
      for (int i = 0; i < 4; ++i)
#pragma unroll
        for (int reg = 0; reg < 4; ++reg)
          red[cg][(mt * 16 + lrow + reg) * 68 + i * 16 + lcol] = cacc[mt][i][reg];
  }
  __syncthreads();
  if (half == 1) {
#pragma unroll
    for (int mt = 0; mt < 4; ++mt)
#pragma unroll
      for (int i = 0; i < 4; ++i)
#pragma unroll
        for (int reg = 0; reg < 4; ++reg) {
          int row = mt * 16 + lrow + reg;
          int col = i * 16 + lcol;
          float v = red[cg][row * 68 + col] + cacc[mt][i][reg];
          out[(rb * 64 + row) * OUT_D + cg * 64 + col] = v;
        }
  }
}

// ===========================================================================
extern "C" void kernel_launch(void* const* d_in, const int* in_sizes, int n_in,
                              void* d_out, int out_size, void* d_ws, size_t ws_size,
                              hipStream_t stream) {
  const float* x      = (const float*)d_in[0];
  const float* dd     = (const float*)d_in[1];
  const float* dp     = (const float*)d_in[2];
  const float* dists  = (const float*)d_in[3];
  const float* sigma  = (const float*)d_in[4];
  const float* kappa  = (const float*)d_in[5];
  const float* phi    = (const float*)d_in[6];
  const float* W      = (const float*)d_in[7];
  const int*   nh     = (const int*)d_in[8];
  float*       out    = (float*)d_out;

  uint4* Bws = (uint4*)d_ws;                       // 1 MB of B-fragments
  uint4* Aws = (uint4*)((char*)d_ws + (1 << 20));  // 64 MB A, stream layout

  pack_B_kernel<<<64, 256, 0, stream>>>(W, Bws);
  agg_kernel<<<N_OUTP / 8, 256, 0, stream>>>(
      x, dd, dp, dists, sigma, kappa, phi, nh, Aws);
  gemm_kernel<<<N_OUTP / 64, 512, 0, stream>>>(Aws, Bws, out);
}

// Round 14
// 57.953 us; speedup vs baseline: 1.4483x; 1.0240x over previous
//
#include <hip/hip_runtime.h>
#include <hip/hip_bf16.h>

// Problem constants
#define N_IN   65536
#define N_OUTP 16384
#define KNB    16
#define FDIM   64
#define M_DIM  32          // N_DIST * N_PHI
#define KDIM   2048        // M_DIM * FDIM
#define OUT_D  256

typedef __bf16 bf16x8_t __attribute__((ext_vector_type(8)));
typedef float  f32x4_t  __attribute__((ext_vector_type(4)));
typedef float  f32x2_t  __attribute__((ext_vector_type(2)));

// ---------------------------------------------------------------------------
// A storage ("stream" layout): per 16-row tile T (=row>>4), per K32-chunk kk,
// 64 lanes x 16B. Lane l holds row (l&15), kg in [kk*32+(l>>4)*8, +8).
// u128 index = T*4096 + kk*64 + l.
// ---------------------------------------------------------------------------

__device__ __forceinline__ unsigned pk2(float a, float b) {
  __bf16 b0 = (__bf16)a, b1 = (__bf16)b;
  return ((unsigned)__builtin_bit_cast(unsigned short, b1) << 16) |
          (unsigned)__builtin_bit_cast(unsigned short, b0);
}
__device__ __forceinline__ float ulo(unsigned u) {
  return __builtin_bit_cast(float, u << 16);
}
__device__ __forceinline__ float uhi(unsigned u) {
  return __builtin_bit_cast(float, u & 0xffff0000u);
}

// ---------------------------------------------------------------------------
// agg v7 = R10's agg (f32 wbuf, bf16 xpk, no swizzle, lb(256,4)) with:
//   (1) fused-denominator einsum: den[mi] += w inside the k-loop; normalize
//       phase + its barrier DELETED; acc scaled by 1/(den+1e-9) at epilogue.
//   (2) pack_B folded in: blocks 0..63 run the B-fragment pack after their
//       agg work (LDS reused after a barrier). Saves one kernel launch.
//   wbuf strides (f32): r8*580, k*36 ; xpk strides (u32): r8*576, k*36
// ---------------------------------------------------------------------------
#define WST 580
#define WKS 36
#define XPS 576
#define XPK 36
#define AGG_LDS 36992   // 18560 (wbuf) + 18432 (xpk); pack wlds 33280 fits

__global__ __launch_bounds__(256, 4) void agg_kernel(
    const float* __restrict__ x,
    const float* __restrict__ d_dists,
    const float* __restrict__ d_phi,
    const float* __restrict__ dists,
    const float* __restrict__ sigma_p,
    const float* __restrict__ kappa_p,
    const float* __restrict__ phi,
    const float* __restrict__ W,
    const int*   __restrict__ nh_idx,
    uint4*       __restrict__ Aws,     // stream layout
    uint4*       __restrict__ Bws)     // B-fragments (written by blocks 0-63)
{
  __shared__ __align__(16) char smem_raw[AGG_LDS];
  float*    wbuf = (float*)smem_raw;               // 8*580 f32
  unsigned* xpk  = (unsigned*)(smem_raw + 18560);  // 8*576 u32

  const int t  = threadIdx.x;
  const int n0 = blockIdx.x * 8;
  const int T  = blockIdx.x >> 1;          // 16-row tile index
  const int r0 = (blockIdx.x & 1) * 8;     // row offset within tile

  // ---- Phase 0a: issue x gather early. (h=t&1, gk=(t>>1)&15, gr8=t>>5)
  const int h = t & 1, gk = (t >> 1) & 15, gr8 = t >> 5;
  const int gidx = nh_idx[(n0 + gr8) * KNB + gk];
  const float4* xr = (const float4*)x + (size_t)gidx * 16 + h * 8;
  float4 xreg[8];
#pragma unroll
  for (int j = 0; j < 8; ++j) xreg[j] = xr[j];

  // ---- Phase 0b: weights (f32 -> wbuf) while gather is in flight.
  {
    const float sinv = 1.0f / sigma_p[0];
    const float kap  = kappa_p[0];
    float phiv[8], distv[4];
#pragma unroll
    for (int p = 0; p < 8; ++p) phiv[p] = phi[p];
#pragma unroll
    for (int d = 0; d < 4; ++d) distv[d] = dists[d];

    int rk = t >> 1, r8w = rk >> 4, k = rk & 15, rep = t & 1;
    int n = n0 + r8w;
    float dd = d_dists[n * KNB + k];
    float dp = d_phi[n * KNB + k];
    float wp[8];
#pragma unroll
    for (int p = 0; p < 8; ++p) wp[p] = __expf(kap * __cosf(dp - phiv[p]));
#pragma unroll
    for (int dl = 0; dl < 2; ++dl) {
      int d = rep * 2 + dl;
      float td = (dd - distv[d]) * sinv;
      float wd = __expf(-0.5f * td * td);
      float* dst = wbuf + r8w * WST + k * WKS + d * 8;
      *(float4*)(dst)     = make_float4(wd * wp[0], wd * wp[1], wd * wp[2], wd * wp[3]);
      *(float4*)(dst + 4) = make_float4(wd * wp[4], wd * wp[5], wd * wp[6], wd * wp[7]);
    }
  }

  // ---- Phase 0c: commit gather to xpk as packed bf16 (row half h).
  {
    unsigned u[16];
#pragma unroll
    for (int j = 0; j < 8; ++j) {
      u[2 * j]     = pk2(xreg[j].x, xreg[j].y);
      u[2 * j + 1] = pk2(xreg[j].z, xreg[j].w);
    }
    uint4* xd = (uint4*)(xpk + gr8 * XPS + gk * XPK + h * 16);
#pragma unroll
    for (int q = 0; q < 4; ++q)
      xd[q] = make_uint4(u[4 * q], u[4 * q + 1], u[4 * q + 2], u[4 * q + 3]);
  }
  __syncthreads();

  // ---- Phase 1: einsum 8m x 8f per thread with FUSED denominator.
  // thread -> (r8 = t&7, fo = (t>>3)&7 [f-octet], mq = t>>6 [m-quad of 8])
  {
    const int r8 = t & 7, fo = (t >> 3) & 7, mq = t >> 6;
    f32x2_t acc[8][4];
    float   den[8];
#pragma unroll
    for (int mi = 0; mi < 8; ++mi) {
      den[mi] = 0.f;
#pragma unroll
      for (int fj = 0; fj < 4; ++fj) acc[mi][fj] = (f32x2_t){0.f, 0.f};
    }

    const float*    wp_ = wbuf + r8 * WST + mq * 8;
    const unsigned* xp_ = xpk + r8 * XPS + fo * 4;

#pragma unroll 8
    for (int k = 0; k < 16; ++k) {
      float4 wa = *(const float4*)(wp_ + k * WKS);
      float4 wbv = *(const float4*)(wp_ + k * WKS + 4);
      uint4 xu = *(const uint4*)(xp_ + k * XPK);
      float wv[8] = {wa.x, wa.y, wa.z, wa.w, wbv.x, wbv.y, wbv.z, wbv.w};
      f32x2_t xv[4];
      xv[0] = (f32x2_t){ulo(xu.x), uhi(xu.x)};
      xv[1] = (f32x2_t){ulo(xu.y), uhi(xu.y)};
      xv[2] = (f32x2_t){ulo(xu.z), uhi(xu.z)};
      xv[3] = (f32x2_t){ulo(xu.w), uhi(xu.w)};
#pragma unroll
      for (int mi = 0; mi < 8; ++mi) {
        den[mi] += wv[mi];
        f32x2_t wmm = (f32x2_t){wv[mi], wv[mi]};
#pragma unroll
        for (int fj = 0; fj < 4; ++fj)
          acc[mi][fj] += wmm * xv[fj];
      }
    }

    // chunk for (row r0+r8, m = mq*8+mi, f in [fo*8, fo*8+8)):
    // u128 idx = T*4096 + (m*2 + (fo>>2))*64 + (fo&3)*16 + (r0+r8)
    uint4* base = Aws + (size_t)T * 4096 + (fo & 3) * 16 + r0 + r8
                      + (size_t)(fo >> 2) * 64;
#pragma unroll
    for (int mi = 0; mi < 8; ++mi) {
      int m = mq * 8 + mi;
      float wn = 1.0f / (den[mi] + 1e-9f);
      uint4 v;
      v.x = pk2(acc[mi][0][0] * wn, acc[mi][0][1] * wn);
      v.y = pk2(acc[mi][1][0] * wn, acc[mi][1][1] * wn);
      v.z = pk2(acc[mi][2][0] * wn, acc[mi][2][1] * wn);
      v.w = pk2(acc[mi][3][0] * wn, acc[mi][3][1] * wn);
      base[m * 128] = v;
    }
  }

  // ---- Tail (blocks 0..63 only): pack W_out K32-slab kk=blockIdx.x into
  // bf16 B-fragments (coalesced load -> padded LDS -> coalesced frag store).
  if (blockIdx.x < 64) {
    __syncthreads();                       // einsum reads of smem done
    float* wlds = (float*)smem_raw;        // 32*260 f32 = 33280 B
    const int kk = blockIdx.x;

    const float4* Wb = (const float4*)(W + kk * 32 * OUT_D);
#pragma unroll
    for (int i = 0; i < 8; ++i) {
      int idx = i * 256 + t;               // 2048 float4 = 32 rows x 64 col4
      int row = idx >> 6, c4 = idx & 63;
      float4 v = Wb[idx];
      *(float4*)(wlds + row * 260 + c4 * 4) = v;
    }
    __syncthreads();

#pragma unroll
    for (int j = 0; j < 4; ++j) {
      int c  = j * 256 + t;                // chunk within slab, 0..1023
      int l  = c & 63, nt = c >> 6;
      int rr = (l >> 4) * 8, col = nt * 16 + (l & 15);
      union { unsigned short s[8]; uint4 v; } u;
#pragma unroll
      for (int jj = 0; jj < 8; ++jj) {
        __bf16 b = (__bf16)wlds[(rr + jj) * 260 + col];
        u.s[jj] = __builtin_bit_cast(unsigned short, b);
      }
      Bws[(size_t)kk * 1024 + c] = u.v;
    }
  }
}

// ---------------------------------------------------------------------------
// gemm v4 (identical to R10): 256 blocks x 512 threads, K-split wave pairs.
// Block = 64 rows x 256 cols. Wave w: cg = w&3 (64-col group), half = w>>2
// (kk parity); 32 j-iters, cacc[4][4], depth-4 register prefetch.
// Epilogue: half=0 parks partials in padded LDS; barrier; half=1 adds+stores.
// ---------------------------------------------------------------------------
__global__ __launch_bounds__(512, 2) void gemm_kernel(
    const uint4* __restrict__ Astream,
    const uint4* __restrict__ Bws,
    float*       __restrict__ out)
{
  __shared__ float red[4][64 * 68];   // 69632 B

  const int t    = threadIdx.x;
  const int lane = t & 63;
  const int w    = t >> 6;
  const int cg   = w & 3;        // col group (64 cols)
  const int half = w >> 2;       // kk parity
  const int rb   = blockIdx.x;   // 64-row block

  const uint4* pa = Astream + (size_t)(rb * 4) * 4096 + half * 64 + lane;
  const uint4* pb = Bws + (half * 16 + cg * 4) * 64 + lane;

  f32x4_t cacc[4][4];
#pragma unroll
  for (int mt = 0; mt < 4; ++mt)
#pragma unroll
    for (int i = 0; i < 4; ++i)
      cacc[mt][i] = (f32x4_t){0.f, 0.f, 0.f, 0.f};

  uint4 a[4][4], b[4][4];
#pragma unroll
  for (int s = 0; s < 4; ++s) {
#pragma unroll
    for (int mt = 0; mt < 4; ++mt) a[s][mt] = pa[mt * 4096 + s * 128];
#pragma unroll
    for (int i = 0; i < 4; ++i)    b[s][i]  = pb[s * 2048 + i * 64];
  }

#pragma unroll 4
  for (int j = 0; j < 32; ++j) {
    const int s = j & 3;
    bf16x8_t B0 = __builtin_bit_cast(bf16x8_t, b[s][0]);
    bf16x8_t B1 = __builtin_bit_cast(bf16x8_t, b[s][1]);
    bf16x8_t B2 = __builtin_bit_cast(bf16x8_t, b[s][2]);
    bf16x8_t B3 = __builtin_bit_cast(bf16x8_t, b[s][3]);
#pragma unroll
    for (int mt = 0; mt < 4; ++mt) {
      bf16x8_t A = __builtin_bit_cast(bf16x8_t, a[s][mt]);
      cacc[mt][0] = __builtin_amdgcn_mfma_f32_16x16x32_bf16(A, B0, cacc[mt][0], 0, 0, 0);
      cacc[mt][1] = __builtin_amdgcn_mfma_f32_16x16x32_bf16(A, B1, cacc[mt][1], 0, 0, 0);
      cacc[mt][2] = __builtin_amdgcn_mfma_f32_16x16x32_bf16(A, B2, cacc[mt][2], 0, 0, 0);
      cacc[mt][3] = __builtin_amdgcn_mfma_f32_16x16x32_bf16(A, B3, cacc[mt][3], 0, 0, 0);
    }
    if (j < 28) {
#pragma unroll
      for (int mt = 0; mt < 4; ++mt) a[s][mt] = pa[mt * 4096 + (j + 4) * 128];
#pragma unroll
      for (int i = 0; i < 4; ++i)    b[s][i]  = pb[(j + 4) * 2048 + i * 64];
    }
  }

  // C/D layout per 16x16 tile: col = lane&15, row = (lane>>4)*4 + reg
  const int lrow = (lane >> 4) * 4;
  const int lcol = lane & 15;

  if (half == 0) {
#pragma unroll
    for (int mt = 0; mt < 4; ++mt)
#pragma unroll
      for (int i = 0; i < 4; ++i)
#pragma unroll
        for (int reg = 0; reg < 4; ++reg)
          red[cg][(mt * 16 + lrow + reg) * 68 + i * 16 + lcol] = cacc[mt][i][reg];
  }
  __syncthreads();
  if (half == 1) {
#pragma unroll
    for (int mt = 0; mt < 4; ++mt)
#pragma unroll
      for (int i = 0; i < 4; ++i)
#pragma unroll
        for (int reg = 0; reg < 4; ++reg) {
          int row = mt * 16 + lrow + reg;
          int col = i * 16 + lcol;
          float v = red[cg][row * 68 + col] + cacc[mt][i][reg];
          out[(rb * 64 + row) * OUT_D + cg * 64 + col] = v;
        }
  }
}

// ===========================================================================
extern "C" void kernel_launch(void* const* d_in, const int* in_sizes, int n_in,
                              void* d_out, int out_size, void* d_ws, size_t ws_size,
                              hipStream_t stream) {
  const float* x      = (const float*)d_in[0];
  const float* dd     = (const float*)d_in[1];
  const float* dp     = (const float*)d_in[2];
  const float* dists  = (const float*)d_in[3];
  const float* sigma  = (const float*)d_in[4];
  const float* kappa  = (const float*)d_in[5];
  const float* phi    = (const float*)d_in[6];
  const float* W      = (const float*)d_in[7];
  const int*   nh     = (const int*)d_in[8];
  float*       out    = (float*)d_out;

  uint4* Bws = (uint4*)d_ws;                       // 1 MB of B-fragments
  uint4* Aws = (uint4*)((char*)d_ws + (1 << 20));  // 64 MB A, stream layout

  agg_kernel<<<N_OUTP / 8, 256, 0, stream>>>(
      x, dd, dp, dists, sigma, kappa, phi, W, nh, Aws, Bws);
  gemm_kernel<<<N_OUTP / 64, 512, 0, stream>>>(Aws, Bws, out);
}